// Round 1
// baseline (176.375 us; speedup 1.0000x reference)
//
#include <hip/hip_runtime.h>

#define HID   32
#define INCH  128
#define OUTD  8
#define BATCH 512
#define TLEN  512
#define TT    32
#define NCHUNK (TLEN / TT)

// ---------------------------------------------------------------------------
// K1: xp[rt][i] = sum_k seq[rt][k] * W_ih[i][k] + (b_ih[i] + b_hh[i])
// rt in [0, BATCH*TLEN). One thread per row; W_ih accessed at wave-uniform
// indices -> scalar loads (s_load), shared across the wave. Each lane streams
// its row as 32 contiguous float4 loads.
// ---------------------------------------------------------------------------
__global__ __launch_bounds__(256) void rnn_proj_kernel(
    const float* __restrict__ seq, const float* __restrict__ Wih,
    const float* __restrict__ bih, const float* __restrict__ bhh,
    float* __restrict__ xp)
{
    const int row = blockIdx.x * 256 + threadIdx.x;      // 0..262143
    const float4* s4 = (const float4*)seq + (size_t)row * (INCH / 4);
    const float4* w4 = (const float4*)Wih;               // [HID][INCH/4]

    float acc[HID];
    #pragma unroll
    for (int i = 0; i < HID; ++i) acc[i] = bih[i] + bhh[i];  // uniform -> scalar

    #pragma unroll 4
    for (int kq = 0; kq < INCH / 4; ++kq) {
        const float4 s = s4[kq];
        #pragma unroll
        for (int i = 0; i < HID; ++i) {
            const float4 w = w4[i * (INCH / 4) + kq];    // wave-uniform -> s_load
            acc[i] = fmaf(s.x, w.x, acc[i]);
            acc[i] = fmaf(s.y, w.y, acc[i]);
            acc[i] = fmaf(s.z, w.z, acc[i]);
            acc[i] = fmaf(s.w, w.w, acc[i]);
        }
    }

    float4* o4 = (float4*)xp + (size_t)row * (HID / 4);
    #pragma unroll
    for (int iq = 0; iq < HID / 4; ++iq) {
        float4 v;
        v.x = acc[iq * 4 + 0]; v.y = acc[iq * 4 + 1];
        v.z = acc[iq * 4 + 2]; v.w = acc[iq * 4 + 3];
        o4[iq] = v;
    }
}

// ---------------------------------------------------------------------------
// K2: serial recurrence h = relu(xp_t + h @ W_hh^T), then FC head.
// One wave (64 threads) per block, 2 batch rows per wave:
//   lanes 0..31  -> row R0,   i = lane
//   lanes 32..63 -> row R0+1, i = lane-32
// W_hh row i kept in 32 VGPRs per lane. h exchanged through a 64-float LDS
// buffer (write h[i], read whole 32-vector back as 4x float4 broadcast reads).
// xp staged in double-buffered LDS chunks of TT timesteps; global loads for
// chunk c+1 are issued before computing chunk c (latency hidden under the
// ~3200-cycle step loop). Single wave -> no barriers anywhere.
// ---------------------------------------------------------------------------
__global__ __launch_bounds__(64) void rnn_scan_kernel(
    const float* __restrict__ xp, const float* __restrict__ Whh,
    const float* __restrict__ Wfc, const float* __restrict__ bfc,
    float* __restrict__ out)
{
    __shared__ __align__(16) float xpb[2][2][TT * HID];  // [buf][row][tt*32+i]
    __shared__ __align__(16) float hbuf[64];

    const int lane = threadIdx.x;
    const int i = lane & 31;
    const int r = lane >> 5;
    const int R0 = blockIdx.x * 2;

    // W_hh row i -> registers (one-time, L2-cached across blocks)
    float w[HID];
    {
        const float4* W4 = (const float4*)Whh;           // [HID][8]
        #pragma unroll
        for (int q = 0; q < 8; ++q) {
            const float4 t = W4[i * 8 + q];
            w[q * 4 + 0] = t.x; w[q * 4 + 1] = t.y;
            w[q * 4 + 2] = t.z; w[q * 4 + 3] = t.w;
        }
    }

    hbuf[lane] = 0.0f;   // h0 = 0

    const float4* xp4 = (const float4*)xp;
    // stage chunk 0 into regs
    float4 stg[8];
    #pragma unroll
    for (int q = 0; q < 8; ++q) {
        const int f = q * 64 + lane;                     // 0..511 float4s of chunk
        const int ridx = f >> 8, rem = f & 255;
        stg[q] = xp4[((R0 + ridx) * TLEN + 0) * (HID / 4) + rem];
    }

    for (int c = 0; c < NCHUNK; ++c) {
        // regs -> LDS for chunk c
        float4* dst = (float4*)&xpb[c & 1][0][0];
        #pragma unroll
        for (int q = 0; q < 8; ++q) dst[q * 64 + lane] = stg[q];

        // issue global loads for chunk c+1 (consumed next iteration)
        if (c + 1 < NCHUNK) {
            const int t0 = (c + 1) * TT;
            #pragma unroll
            for (int q = 0; q < 8; ++q) {
                const int f = q * 64 + lane;
                const int ridx = f >> 8, rem = f & 255;
                stg[q] = xp4[((R0 + ridx) * TLEN + t0) * (HID / 4) + rem];
            }
        }

        const float* xprow = &xpb[c & 1][r][0];
        const float4* h4 = (const float4*)&hbuf[r * 32];

        #pragma unroll
        for (int tt = 0; tt < TT; ++tt) {
            float a0 = xprow[tt * HID + i];
            float a1 = 0.0f, a2 = 0.0f, a3 = 0.0f;
            #pragma unroll
            for (int q = 0; q < 8; ++q) {
                const float4 hv = h4[q];                 // broadcast ds_read_b128
                a0 = fmaf(w[q * 4 + 0], hv.x, a0);
                a1 = fmaf(w[q * 4 + 1], hv.y, a1);
                a2 = fmaf(w[q * 4 + 2], hv.z, a2);
                a3 = fmaf(w[q * 4 + 3], hv.w, a3);
            }
            const float h = fmaxf((a0 + a1) + (a2 + a3), 0.0f);
            hbuf[lane] = h;                              // for next step
        }
    }

    // FC head: out[b][o] = sum_j h_last[b][j] * W_fc[o][j] + b_fc[o]
    if (lane < 2 * OUTD) {
        const int rr = lane >> 3, o = lane & 7;
        const float* hh = &hbuf[rr * 32];
        float s = bfc[o];
        #pragma unroll
        for (int j = 0; j < HID; ++j) s = fmaf(hh[j], Wfc[o * HID + j], s);
        out[(R0 + rr) * OUTD + o] = s;
    }
}

extern "C" void kernel_launch(void* const* d_in, const int* in_sizes, int n_in,
                              void* d_out, int out_size, void* d_ws, size_t ws_size,
                              hipStream_t stream) {
    const float* seq = (const float*)d_in[0];
    const float* Wih = (const float*)d_in[1];
    const float* Whh = (const float*)d_in[2];
    const float* bih = (const float*)d_in[3];
    const float* bhh = (const float*)d_in[4];
    const float* Wfc = (const float*)d_in[5];
    const float* bfc = (const float*)d_in[6];

    float* xp = (float*)d_ws;   // [BATCH*TLEN][HID] fp32 = 32 MiB scratch

    rnn_proj_kernel<<<dim3((BATCH * TLEN) / 256), dim3(256), 0, stream>>>(
        seq, Wih, bih, bhh, xp);
    rnn_scan_kernel<<<dim3(BATCH / 2), dim3(64), 0, stream>>>(
        xp, Whh, Wfc, bfc, (float*)d_out);
}

// Round 2
// 174.500 us; speedup vs baseline: 1.0107x; 1.0107x over previous
//
#include <hip/hip_runtime.h>

#define HID   32
#define INCH  128
#define OUTD  8
#define BATCH 512
#define TLEN  512
#define TT    32
#define NCHUNK (TLEN / TT)

// ---------------------------------------------------------------------------
// Fused kernel: one block per batch row. 3 waves (192 threads):
//   wave 0      : serial scan  h = relu(xp_t + W_hh h), then FC head
//   waves 1,2   : projection   xp[t][i] = b + sum_k seq[t][k] W_ih[i][k]
// Producer-consumer through double-buffered LDS chunks of TT=32 timesteps.
// Scan broadcasts h via v_readlane (VALU cross-lane, no LDS on the serial
// dependency chain). W_hh row i lives in 32 VGPRs of lane i.
// ---------------------------------------------------------------------------
__global__ __launch_bounds__(192) void rnn_fused_kernel(
    const float* __restrict__ seq, const float* __restrict__ Wih,
    const float* __restrict__ Whh, const float* __restrict__ bih,
    const float* __restrict__ bhh, const float* __restrict__ Wfc,
    const float* __restrict__ bfc, float* __restrict__ out)
{
    __shared__ __align__(16) float wl[HID * INCH];      // W_ih [i][k], 16 KB
    __shared__ __align__(16) float xpb[2][TT * HID];    // chunk dbuf, 8 KB
    __shared__ float bl[HID];
    __shared__ float hfin[HID];

    const int tid  = threadIdx.x;
    const int wid  = tid >> 6;          // wave id 0..2 (uniform per wave)
    const int lane = tid & 63;
    const int row  = blockIdx.x;        // batch row

    // cooperative stage of W_ih + bias
    {
        const float4* w4 = (const float4*)Wih;
        float4* d = (float4*)wl;
        for (int q = tid; q < HID * INCH / 4; q += 192) d[q] = w4[q];
        if (tid < HID) bl[tid] = bih[tid] + bhh[tid];
    }
    __syncthreads();   // barrier #0 (all waves)

    if (wid == 0) {
        // ===================== SCAN WAVE =====================
        const int ch = lane & 31;       // channel; upper half mirrors lower
        float w[HID];
        {
            const float4* W4 = (const float4*)Whh;      // [32][8] float4
            #pragma unroll
            for (int q = 0; q < 8; ++q) {
                const float4 t = W4[ch * 8 + q];
                w[q * 4 + 0] = t.x; w[q * 4 + 1] = t.y;
                w[q * 4 + 2] = t.z; w[q * 4 + 3] = t.w;
            }
        }
        float h = 0.0f;
        __builtin_amdgcn_s_setprio(1);

        for (int c = 0; c < NCHUNK; ++c) {
            __syncthreads();            // chunk c published by proj waves
            const float* xr = xpb[c & 1];

            #pragma unroll 4
            for (int tt = 0; tt < TT; ++tt) {
                const float xv = xr[tt * HID + ch];     // broadcast-friendly
                float a0 = xv, a1 = 0.0f, a2 = 0.0f, a3 = 0.0f;
                // h[j] broadcast via v_readlane -> SGPR, consumed by v_fmac
                #define RL(J, A) { \
                    const float hj = __int_as_float( \
                        __builtin_amdgcn_readlane(__float_as_int(h), (J))); \
                    A = fmaf(w[(J)], hj, A); }
                RL(0, a0)  RL(1, a1)  RL(2, a2)  RL(3, a3)
                RL(4, a0)  RL(5, a1)  RL(6, a2)  RL(7, a3)
                RL(8, a0)  RL(9, a1)  RL(10, a2) RL(11, a3)
                RL(12, a0) RL(13, a1) RL(14, a2) RL(15, a3)
                RL(16, a0) RL(17, a1) RL(18, a2) RL(19, a3)
                RL(20, a0) RL(21, a1) RL(22, a2) RL(23, a3)
                RL(24, a0) RL(25, a1) RL(26, a2) RL(27, a3)
                RL(28, a0) RL(29, a1) RL(30, a2) RL(31, a3)
                #undef RL
                h = fmaxf((a0 + a1) + (a2 + a3), 0.0f);
            }
        }
        __builtin_amdgcn_s_setprio(0);

        if (lane < HID) hfin[lane] = h;     // lanes 0..31 hold h[lane]
        // single-wave LDS dependency: compiler inserts lgkmcnt wait
        if (lane < OUTD) {
            float s = bfc[lane];
            #pragma unroll
            for (int j = 0; j < HID; ++j)
                s = fmaf(hfin[j], Wfc[lane * HID + j], s);
            out[row * OUTD + lane] = s;
        }
    } else {
        // ===================== PROJ WAVES (wid 1,2) =====================
        const int t_l = lane & 31;                   // timestep within chunk
        const int q   = (wid - 1) * 2 + (lane >> 5); // i-quarter 0..3
        float bias[8];
        #pragma unroll
        for (int j = 0; j < 8; ++j) bias[j] = bl[q * 8 + j];

        for (int c = 0; c < NCHUNK; ++c) {
            const float4* s4 = (const float4*)(seq +
                ((size_t)row * TLEN + (size_t)c * TT + t_l) * INCH);
            float acc[8];
            #pragma unroll
            for (int j = 0; j < 8; ++j) acc[j] = bias[j];

            #pragma unroll 4
            for (int kq = 0; kq < INCH / 4; ++kq) {
                const float4 s = s4[kq];
                #pragma unroll
                for (int j = 0; j < 8; ++j) {
                    const float4 wv =
                        ((const float4*)wl)[(q * 8 + j) * (INCH / 4) + kq];
                    acc[j] = fmaf(s.x, wv.x, acc[j]);
                    acc[j] = fmaf(s.y, wv.y, acc[j]);
                    acc[j] = fmaf(s.z, wv.z, acc[j]);
                    acc[j] = fmaf(s.w, wv.w, acc[j]);
                }
            }

            float4* dst = (float4*)&xpb[c & 1][t_l * HID + q * 8];
            dst[0] = make_float4(acc[0], acc[1], acc[2], acc[3]);
            dst[1] = make_float4(acc[4], acc[5], acc[6], acc[7]);
            __syncthreads();            // publish chunk c
        }
    }
}

extern "C" void kernel_launch(void* const* d_in, const int* in_sizes, int n_in,
                              void* d_out, int out_size, void* d_ws, size_t ws_size,
                              hipStream_t stream) {
    const float* seq = (const float*)d_in[0];
    const float* Wih = (const float*)d_in[1];
    const float* Whh = (const float*)d_in[2];
    const float* bih = (const float*)d_in[3];
    const float* bhh = (const float*)d_in[4];
    const float* Wfc = (const float*)d_in[5];
    const float* bfc = (const float*)d_in[6];

    rnn_fused_kernel<<<dim3(BATCH), dim3(192), 0, stream>>>(
        seq, Wih, Whh, bih, bhh, Wfc, bfc, (float*)d_out);
}

// Round 3
// 68.191 us; speedup vs baseline: 2.5865x; 2.5590x over previous
//
#include <hip/hip_runtime.h>

#define HID   32
#define INCH  128
#define OUTD  8
#define BATCH 512
#define TLEN  512
#define TT    32
#define NCHUNK (TLEN / TT)

typedef __attribute__((ext_vector_type(8)))  short  short8_t;
typedef __attribute__((ext_vector_type(16))) float  f32x16_t;

// Split fp32 -> bf16 hi (bit-truncate) + bf16 lo (truncated residual).
// a*b ~= ah*bh + ah*bl + al*bh ; dropped al*bl ~ 2^-16 relative.
__device__ __forceinline__ void split8(const float4 f0, const float4 f1,
                                       short8_t* hi, short8_t* lo)
{
    float x[8] = {f0.x, f0.y, f0.z, f0.w, f1.x, f1.y, f1.z, f1.w};
    short8_t h, l;
    #pragma unroll
    for (int e = 0; e < 8; ++e) {
        const unsigned u  = __float_as_uint(x[e]);
        const unsigned hb = u & 0xFFFF0000u;
        h[e] = (short)(u >> 16);
        const float r = x[e] - __uint_as_float(hb);
        l[e] = (short)(__float_as_uint(r) >> 16);
    }
    *hi = h; *lo = l;
}

// ---------------------------------------------------------------------------
// One block per batch row; 2 waves:
//   wave 0: serial scan h = relu(xp_t + W_hh h) via v_readlane broadcast,
//           then the 8-wide FC head (also via readlane).
//   wave 1: projection as split-bf16 MFMA: per 32-t chunk, a 32x32x128 GEMM
//           done with 24 v_mfma_f32_32x32x16_bf16 (3 per K=16 block).
// Producer-consumer through double-buffered LDS xpb chunks.
// ---------------------------------------------------------------------------
__global__ __launch_bounds__(128, 1) void rnn_fused_kernel(
    const float* __restrict__ seq, const float* __restrict__ Wih,
    const float* __restrict__ Whh, const float* __restrict__ bih,
    const float* __restrict__ bhh, const float* __restrict__ Wfc,
    const float* __restrict__ bfc, float* __restrict__ out)
{
    __shared__ __align__(16) float xpb[2][TT * HID];   // 8 KB double buffer

    const int tid  = threadIdx.x;
    const int wid  = tid >> 6;
    const int l    = tid & 63;
    const int row  = blockIdx.x;

    if (wid == 0) {
        // ============================ SCAN ============================
        const int ch = l & 31;
        float w[HID];
        {
            const float4* W4 = (const float4*)Whh;     // [32][8] float4
            #pragma unroll
            for (int q = 0; q < 8; ++q) {
                const float4 t4 = W4[ch * 8 + q];
                w[q * 4 + 0] = t4.x; w[q * 4 + 1] = t4.y;
                w[q * 4 + 2] = t4.z; w[q * 4 + 3] = t4.w;
            }
        }
        float h = 0.0f;
        __builtin_amdgcn_s_setprio(1);

        for (int c = 0; c < NCHUNK; ++c) {
            __syncthreads();                           // chunk c ready
            const float* xb = xpb[c & 1];
            float xv = xb[ch];                         // t = 0
            #pragma unroll 4
            for (int tt = 0; tt < TT; ++tt) {
                // prefetch next step's xv (hides ds_read latency under chain)
                const float xvn = xb[(((tt + 1) & 31) * HID) + ch];
                float a0 = xv, a1 = 0.0f, a2 = 0.0f, a3 = 0.0f;
                #pragma unroll
                for (int j = 0; j < HID; j += 4) {
                    const float h0 = __uint_as_float(
                        __builtin_amdgcn_readlane(__float_as_uint(h), j + 0));
                    const float h1 = __uint_as_float(
                        __builtin_amdgcn_readlane(__float_as_uint(h), j + 1));
                    const float h2 = __uint_as_float(
                        __builtin_amdgcn_readlane(__float_as_uint(h), j + 2));
                    const float h3 = __uint_as_float(
                        __builtin_amdgcn_readlane(__float_as_uint(h), j + 3));
                    a0 = fmaf(w[j + 0], h0, a0);
                    a1 = fmaf(w[j + 1], h1, a1);
                    a2 = fmaf(w[j + 2], h2, a2);
                    a3 = fmaf(w[j + 3], h3, a3);
                }
                h = fmaxf((a0 + a1) + (a2 + a3), 0.0f);
                xv = xvn;
            }
        }
        __builtin_amdgcn_s_setprio(0);

        // FC head: lane o (0..7) computes out[row][o]; h[j] via readlane.
        float s = bfc[l & 7];
        #pragma unroll
        for (int j = 0; j < HID; ++j) {
            const float hj = __uint_as_float(
                __builtin_amdgcn_readlane(__float_as_uint(h), j));
            s = fmaf(hj, Wfc[(l & 7) * HID + j], s);
        }
        if (l < OUTD) out[row * OUTD + l] = s;
    } else {
        // ============================ PROJ ============================
        const int trow  = l & 31;          // timestep within chunk (A row)
        const int khalf = l >> 5;          // k-half selector
        const int irow  = l & 31;          // channel (B col / W_ih row)

        // W_ih fragments (hi+lo), kept in VGPRs for the whole kernel.
        short8_t whi[8], wlo[8];
        #pragma unroll
        for (int kb = 0; kb < 8; ++kb) {
            const float* wp = Wih + irow * INCH + kb * 16 + khalf * 8;
            const float4 f0 = *(const float4*)(wp);
            const float4 f1 = *(const float4*)(wp + 4);
            split8(f0, f1, &whi[kb], &wlo[kb]);
        }
        const float biasv = bih[irow] + bhh[irow];

        for (int c = 0; c < NCHUNK; ++c) {
            const float* sp = seq +
                ((size_t)row * TLEN + (size_t)c * TT + trow) * INCH + khalf * 8;
            short8_t ahi[8], alo[8];
            #pragma unroll
            for (int kb = 0; kb < 8; ++kb) {
                const float4 f0 = *(const float4*)(sp + kb * 16);
                const float4 f1 = *(const float4*)(sp + kb * 16 + 4);
                split8(f0, f1, &ahi[kb], &alo[kb]);
            }

            f32x16_t acc;
            #pragma unroll
            for (int r2 = 0; r2 < 16; ++r2) acc[r2] = biasv;
            #pragma unroll
            for (int kb = 0; kb < 8; ++kb) {
                acc = __builtin_amdgcn_mfma_f32_32x32x16_bf16(ahi[kb], whi[kb], acc, 0, 0, 0);
                acc = __builtin_amdgcn_mfma_f32_32x32x16_bf16(ahi[kb], wlo[kb], acc, 0, 0, 0);
                acc = __builtin_amdgcn_mfma_f32_32x32x16_bf16(alo[kb], whi[kb], acc, 0, 0, 0);
            }

            // D layout (HW-verified): col = lane&31, row = (r&3)+8*(r>>2)+4*(lane>>5)
            float* xb = xpb[c & 1];
            #pragma unroll
            for (int r2 = 0; r2 < 16; ++r2) {
                const int tp = (r2 & 3) + 8 * (r2 >> 2) + 4 * khalf;
                xb[tp * HID + irow] = acc[r2];
            }
            __syncthreads();                           // publish chunk c
        }
    }
}

extern "C" void kernel_launch(void* const* d_in, const int* in_sizes, int n_in,
                              void* d_out, int out_size, void* d_ws, size_t ws_size,
                              hipStream_t stream) {
    const float* seq = (const float*)d_in[0];
    const float* Wih = (const float*)d_in[1];
    const float* Whh = (const float*)d_in[2];
    const float* bih = (const float*)d_in[3];
    const float* bhh = (const float*)d_in[4];
    const float* Wfc = (const float*)d_in[5];
    const float* bfc = (const float*)d_in[6];

    rnn_fused_kernel<<<dim3(BATCH), dim3(128), 0, stream>>>(
        seq, Wih, Whh, bih, bhh, Wfc, bfc, (float*)d_out);
}

// Round 4
// 59.044 us; speedup vs baseline: 2.9872x; 1.1549x over previous
//
#include <hip/hip_runtime.h>

#define HID   32
#define INCH  128
#define OUTD  8
#define BATCH 512
#define TLEN  512
#define TT    32
#define NCHUNK (TLEN / TT)

typedef __attribute__((ext_vector_type(2)))  float  f32x2;
typedef __attribute__((ext_vector_type(4)))  float  vf4;
typedef __attribute__((ext_vector_type(8)))  short  short8_t;
typedef __attribute__((ext_vector_type(16))) float  f32x16_t;

// Split fp32 -> bf16 hi (bit-truncate) + bf16 lo (truncated residual).
__device__ __forceinline__ void split8(const float4 f0, const float4 f1,
                                       short8_t* hi, short8_t* lo)
{
    float x[8] = {f0.x, f0.y, f0.z, f0.w, f1.x, f1.y, f1.z, f1.w};
    short8_t h, l;
    #pragma unroll
    for (int e = 0; e < 8; ++e) {
        const unsigned u  = __float_as_uint(x[e]);
        const unsigned hb = u & 0xFFFF0000u;
        h[e] = (short)(u >> 16);
        const float r = x[e] - __uint_as_float(hb);
        l[e] = (short)(__float_as_uint(r) >> 16);
    }
    *hi = h; *lo = l;
}

// ---------------------------------------------------------------------------
// One block per batch row; 2 waves:
//   wave 0: serial scan h = relu(xp_t + W_hh h). LDS-broadcast h exchange:
//           lane l writes hlds[l] (two identical 32-float copies, one per
//           half-wave); each half reads its own copy -> conflict-free, no
//           barrier (single wave, in-order LDS pipe). Matvec as f32x2 packed
//           FMA (v_pk_fma_f32) to halve issue on the serial chain.
//   wave 1: projection as split-bf16 MFMA (unchanged from round 3).
// ---------------------------------------------------------------------------
__global__ __launch_bounds__(128, 1) void rnn_fused_kernel(
    const float* __restrict__ seq, const float* __restrict__ Wih,
    const float* __restrict__ Whh, const float* __restrict__ bih,
    const float* __restrict__ bhh, const float* __restrict__ Wfc,
    const float* __restrict__ bfc, float* __restrict__ out)
{
    __shared__ __align__(16) float xpb[2][TT * HID];   // 8 KB double buffer
    __shared__ __align__(16) float hlds[64];           // 2 copies of h

    const int tid  = threadIdx.x;
    const int wid  = tid >> 6;
    const int l    = tid & 63;
    const int row  = blockIdx.x;

    if (wid == 0) {
        // ============================ SCAN ============================
        const int ch = l & 31;
        // W_hh row ch as 16 f32x2 pairs (w2[p] = {W[ch][2p], W[ch][2p+1]})
        f32x2 w2[16];
        {
            const vf4* W4 = (const vf4*)(Whh + ch * HID);
            #pragma unroll
            for (int q = 0; q < 8; ++q) {
                const vf4 t = W4[q];
                w2[2 * q + 0] = t.xy;
                w2[2 * q + 1] = t.zw;
            }
        }
        hlds[l] = 0.0f;                                // h0 = 0 (both copies)
        const vf4* h4 = (const vf4*)&hlds[(l >> 5) * 32];  // my half's copy

        __builtin_amdgcn_s_setprio(1);
        for (int c = 0; c < NCHUNK; ++c) {
            __syncthreads();                           // chunk c published
            const float* xb = xpb[c & 1];
            float xv = xb[ch];                         // t = 0 (overlaps h-reads)
            #pragma unroll
            for (int tt = 0; tt < TT; ++tt) {
                // prefetch next step's x (off the serial chain)
                const float xvn = (tt < TT - 1) ? xb[(tt + 1) * HID + ch] : 0.0f;
                f32x2 a0 = {xv, 0.0f};
                f32x2 a1 = {0.0f, 0.0f}, a2 = {0.0f, 0.0f}, a3 = {0.0f, 0.0f};
                #pragma unroll
                for (int q = 0; q < 8; ++q) {
                    const vf4 hq = h4[q];              // ds_read_b128 broadcast
                    a0 = w2[2 * q + 0] * hq.xy + a0;   // v_pk_fma_f32
                    a1 = w2[2 * q + 1] * hq.zw + a1;
                    // rotate accumulators to keep 4 independent chains
                    const f32x2 t0 = a0; a0 = a2; a2 = t0;
                    const f32x2 t1 = a1; a1 = a3; a3 = t1;
                }
                const f32x2 s01 = a0 + a1;
                const f32x2 s23 = a2 + a3;
                const f32x2 s = s01 + s23;
                const float h = fmaxf(s.x + s.y, 0.0f);
                hlds[l] = h;                           // publish for next step
                xv = xvn;
            }
        }
        __builtin_amdgcn_s_setprio(0);

        // FC head: lane o (0..7) computes out[row][o] from hlds copy 0.
        if (l < OUTD) {
            float s = bfc[l];
            #pragma unroll
            for (int j = 0; j < HID; ++j)
                s = fmaf(hlds[j], Wfc[l * HID + j], s);
            out[row * OUTD + l] = s;
        }
    } else {
        // ============================ PROJ ============================
        const int trow  = l & 31;          // timestep within chunk (A row)
        const int khalf = l >> 5;          // k-half selector
        const int irow  = l & 31;          // channel (B col / W_ih row)

        short8_t whi[8], wlo[8];
        #pragma unroll
        for (int kb = 0; kb < 8; ++kb) {
            const float* wp = Wih + irow * INCH + kb * 16 + khalf * 8;
            const float4 f0 = *(const float4*)(wp);
            const float4 f1 = *(const float4*)(wp + 4);
            split8(f0, f1, &whi[kb], &wlo[kb]);
        }
        const float biasv = bih[irow] + bhh[irow];

        for (int c = 0; c < NCHUNK; ++c) {
            const float* sp = seq +
                ((size_t)row * TLEN + (size_t)c * TT + trow) * INCH + khalf * 8;
            short8_t ahi[8], alo[8];
            #pragma unroll
            for (int kb = 0; kb < 8; ++kb) {
                const float4 f0 = *(const float4*)(sp + kb * 16);
                const float4 f1 = *(const float4*)(sp + kb * 16 + 4);
                split8(f0, f1, &ahi[kb], &alo[kb]);
            }

            f32x16_t acc;
            #pragma unroll
            for (int r2 = 0; r2 < 16; ++r2) acc[r2] = biasv;
            #pragma unroll
            for (int kb = 0; kb < 8; ++kb) {
                acc = __builtin_amdgcn_mfma_f32_32x32x16_bf16(ahi[kb], whi[kb], acc, 0, 0, 0);
                acc = __builtin_amdgcn_mfma_f32_32x32x16_bf16(ahi[kb], wlo[kb], acc, 0, 0, 0);
                acc = __builtin_amdgcn_mfma_f32_32x32x16_bf16(alo[kb], whi[kb], acc, 0, 0, 0);
            }

            // D layout: col = lane&31, row = (r&3)+8*(r>>2)+4*(lane>>5)
            float* xb = xpb[c & 1];
            #pragma unroll
            for (int r2 = 0; r2 < 16; ++r2) {
                const int tp = (r2 & 3) + 8 * (r2 >> 2) + 4 * khalf;
                xb[tp * HID + irow] = acc[r2];
            }
            __syncthreads();                           // publish chunk c
        }
    }
}

extern "C" void kernel_launch(void* const* d_in, const int* in_sizes, int n_in,
                              void* d_out, int out_size, void* d_ws, size_t ws_size,
                              hipStream_t stream) {
    const float* seq = (const float*)d_in[0];
    const float* Wih = (const float*)d_in[1];
    const float* Whh = (const float*)d_in[2];
    const float* bih = (const float*)d_in[3];
    const float* bhh = (const float*)d_in[4];
    const float* Wfc = (const float*)d_in[5];
    const float* bfc = (const float*)d_in[6];

    rnn_fused_kernel<<<dim3(BATCH), dim3(128), 0, stream>>>(
        seq, Wih, Whh, bih, bhh, Wfc, bfc, (float*)d_out);
}

// Round 6
// 53.288 us; speedup vs baseline: 3.3099x; 1.1080x over previous
//
#include <hip/hip_runtime.h>

#define HID   32
#define INCH  128
#define OUTD  8
#define BATCH 512
#define TLEN  512
#define TT    32
#define NCHUNK (TLEN / TT)

typedef __attribute__((ext_vector_type(2)))  float  f32x2;
typedef __attribute__((ext_vector_type(4)))  float  vf4;
typedef __attribute__((ext_vector_type(8)))  short  short8_t;
typedef __attribute__((ext_vector_type(16))) float  f32x16_t;
typedef __attribute__((ext_vector_type(2)))  int    i32x2;

// Combine per-half partial sums: returns p[own] + p[partner-half lane].
__device__ __forceinline__ float half_combine(float p)
{
#if __has_builtin(__builtin_amdgcn_permlane32_swap)
    // Functional form of v_permlane32_swap_b32: returns {vdst', vsrc'}.
    // With both inputs = p: r[0]+r[1] = p_own + p_partner on every lane.
    i32x2 r = __builtin_amdgcn_permlane32_swap(
        __float_as_int(p), __float_as_int(p), false, false);
    return __int_as_float(r[0]) + __int_as_float(r[1]);
#else
    return p + __shfl_xor(p, 32, 64);
#endif
}

// Split fp32 -> bf16 hi (bit-truncate) + bf16 lo (truncated residual).
__device__ __forceinline__ void split8(const float4 f0, const float4 f1,
                                       short8_t* hi, short8_t* lo)
{
    float x[8] = {f0.x, f0.y, f0.z, f0.w, f1.x, f1.y, f1.z, f1.w};
    short8_t h, l;
    #pragma unroll
    for (int e = 0; e < 8; ++e) {
        const unsigned u  = __float_as_uint(x[e]);
        const unsigned hb = u & 0xFFFF0000u;
        h[e] = (short)(u >> 16);
        const float r = x[e] - __uint_as_float(hb);
        l[e] = (short)(__float_as_uint(r) >> 16);
    }
    *hi = h; *lo = l;
}

// ---------------------------------------------------------------------------
// One block per batch row; 2 waves.
//   wave 0 (scan): h = relu(x_t + W_hh h), fp32. Per-step serial chain:
//     - j-range split across half-waves (4 ds_read_b128 on the chain)
//     - cross-half combine via permlane32_swap intrinsic (VALU latency)
//     - x_t preloaded per chunk into registers from a transposed,
//       XOR-swizzled LDS tile (off the serial chain)
//   wave 1 (proj): split-bf16 MFMA 32x32x128 GEMM per chunk,
//     D stored transposed as 4x ds_write_b128 per lane.
// ---------------------------------------------------------------------------
__global__ __launch_bounds__(128, 1) void rnn_fused_kernel(
    const float* __restrict__ seq, const float* __restrict__ Wih,
    const float* __restrict__ Whh, const float* __restrict__ bih,
    const float* __restrict__ bhh, const float* __restrict__ Wfc,
    const float* __restrict__ bfc, float* __restrict__ out)
{
    __shared__ __align__(16) float xpb[2][TT * HID];   // transposed [ch][t], 8 KB
    __shared__ __align__(16) float hlds[64];           // 2 copies of h

    const int tid  = threadIdx.x;
    const int wid  = tid >> 6;
    const int l    = tid & 63;
    const int row  = blockIdx.x;

    if (wid == 0) {
        // ============================ SCAN ============================
        const int ch    = l & 31;
        const int half  = l >> 5;
        const int jbase = half * 16;
        const int m     = 4 * (ch & 7);                 // x swizzle (dwords)

        // W_hh[ch][jbase .. jbase+15] as 8 f32x2
        f32x2 w2[8];
        {
            const vf4* W4 = (const vf4*)(Whh + ch * HID + jbase);
            #pragma unroll
            for (int q = 0; q < 4; ++q) {
                const vf4 t = W4[q];
                w2[2 * q + 0] = t.xy;
                w2[2 * q + 1] = t.zw;
            }
        }

        hlds[l] = 0.0f;                                 // h0 = 0 (both copies)
        // low half reads h[0..15] (copy 0), high half h[16..31] (copy 1)
        const vf4* h4 = (const vf4*)&hlds[half * 48];

        __builtin_amdgcn_s_setprio(1);
        for (int c = 0; c < NCHUNK; ++c) {
            __syncthreads();                            // chunk c published
            const float* xb = xpb[c & 1] + ch * TT;     // my channel's column
            vf4 xq[8];
            xq[0] = *(const vf4*)(xb + (0 ^ m));        // x[0..3]

            #pragma unroll
            for (int tt = 0; tt < TT; ++tt) {
                const float xv = xq[tt >> 2][tt & 3];
                const vf4 h0 = h4[0];
                const vf4 h1 = h4[1];
                const vf4 h2 = h4[2];
                const vf4 h3 = h4[3];
                f32x2 a0 = w2[0] * h0.xy;
                f32x2 a1 = w2[1] * h0.zw;
                a0 = w2[2] * h1.xy + a0;
                a1 = w2[3] * h1.zw + a1;
                a0 = w2[4] * h2.xy + a0;
                a1 = w2[5] * h2.zw + a1;
                a0 = w2[6] * h3.xy + a0;
                a1 = w2[7] * h3.zw + a1;
                const f32x2 s2 = a0 + a1;
                const float p = s2.x + s2.y;            // my half's partial
                const float tot = half_combine(p);      // own + partner
                const float hn = fmaxf(xv + tot, 0.0f);
                hlds[l] = hn;                           // publish for next step
                if (tt < 7)                             // off-chain x prefetch
                    xq[tt + 1] = *(const vf4*)(xb + (((tt + 1) * 4) ^ m));
            }
        }
        __builtin_amdgcn_s_setprio(0);

        // FC head: lane o (0..7) computes out[row][o] from hlds copy 0.
        if (l < OUTD) {
            float s = bfc[l];
            #pragma unroll
            for (int j = 0; j < HID; ++j)
                s = fmaf(hlds[j], Wfc[l * HID + j], s);
            out[row * OUTD + l] = s;
        }
    } else {
        // ============================ PROJ ============================
        const int trow  = l & 31;          // timestep within chunk (A row)
        const int khalf = l >> 5;          // k-half selector
        const int irow  = l & 31;          // channel (B col / W_ih row)

        short8_t whi[8], wlo[8];
        #pragma unroll
        for (int kb = 0; kb < 8; ++kb) {
            const float* wp = Wih + irow * INCH + kb * 16 + khalf * 8;
            const float4 f0 = *(const float4*)(wp);
            const float4 f1 = *(const float4*)(wp + 4);
            split8(f0, f1, &whi[kb], &wlo[kb]);
        }
        const float biasv = bih[irow] + bhh[irow];
        const int m2 = 4 * (irow & 7);                  // store swizzle

        for (int c = 0; c < NCHUNK; ++c) {
            const float* sp = seq +
                ((size_t)row * TLEN + (size_t)c * TT + trow) * INCH + khalf * 8;
            short8_t ahi[8], alo[8];
            #pragma unroll
            for (int kb = 0; kb < 8; ++kb) {
                const float4 f0 = *(const float4*)(sp + kb * 16);
                const float4 f1 = *(const float4*)(sp + kb * 16 + 4);
                split8(f0, f1, &ahi[kb], &alo[kb]);
            }

            f32x16_t acc;
            #pragma unroll
            for (int r2 = 0; r2 < 16; ++r2) acc[r2] = biasv;
            #pragma unroll
            for (int kb = 0; kb < 8; ++kb) {
                acc = __builtin_amdgcn_mfma_f32_32x32x16_bf16(ahi[kb], whi[kb], acc, 0, 0, 0);
                acc = __builtin_amdgcn_mfma_f32_32x32x16_bf16(ahi[kb], wlo[kb], acc, 0, 0, 0);
                acc = __builtin_amdgcn_mfma_f32_32x32x16_bf16(alo[kb], whi[kb], acc, 0, 0, 0);
            }

            // D: lane holds 16 timesteps of channel irow -> transposed store,
            // 4x ds_write_b128 at t0 = 8g + 4*khalf (XOR-swizzled)
            float* xbT = xpb[c & 1] + irow * TT;
            #pragma unroll
            for (int g = 0; g < 4; ++g) {
                const int t0 = 8 * g + 4 * khalf;
                vf4 v;
                v.x = acc[4 * g + 0]; v.y = acc[4 * g + 1];
                v.z = acc[4 * g + 2]; v.w = acc[4 * g + 3];
                *(vf4*)(xbT + (t0 ^ m2)) = v;
            }
            __syncthreads();                            // publish chunk c
        }
    }
}

extern "C" void kernel_launch(void* const* d_in, const int* in_sizes, int n_in,
                              void* d_out, int out_size, void* d_ws, size_t ws_size,
                              hipStream_t stream) {
    const float* seq = (const float*)d_in[0];
    const float* Wih = (const float*)d_in[1];
    const float* Whh = (const float*)d_in[2];
    const float* bih = (const float*)d_in[3];
    const float* bhh = (const float*)d_in[4];
    const float* Wfc = (const float*)d_in[5];
    const float* bfc = (const float*)d_in[6];

    rnn_fused_kernel<<<dim3(BATCH), dim3(128), 0, stream>>>(
        seq, Wih, Whh, bih, bhh, Wfc, bfc, (float*)d_out);
}